// Round 16
// baseline (193.611 us; speedup 1.0000x reference)
//
#include <hip/hip_runtime.h>

typedef __attribute__((ext_vector_type(8))) _Float16 f16x8;
typedef __attribute__((ext_vector_type(4))) float f32x4;

#define GLOBAL_AS __attribute__((address_space(1)))
#define LDS_AS __attribute__((address_space(3)))

static constexpr int Bb = 4, LL = 2048, DD = 1024, DI = 2048, DS = 16;
static constexpr int MROWS = Bb * LL;   // 8192
static constexpr int N1 = 2 * DI;       // 4096
static constexpr int K1 = DD;           // 1024
static constexpr int N2 = DD;           // 1024
static constexpr int K2 = DI;           // 2048

__device__ __forceinline__ unsigned short f2h(float f) {
  _Float16 h = (_Float16)f;
  union { _Float16 h; unsigned short u; } c; c.h = h;
  return c.u;
}
__device__ __forceinline__ float h2f(unsigned short u) {
  union { unsigned short u; _Float16 h; } c; c.u = u;
  return (float)c.h;
}

// ---------------- LayerNorm -> fp16 A1h [8192][1024] ------------------------
__global__ __launch_bounds__(256) void ln_half_kernel(
    const float* __restrict__ x, const float* __restrict__ lnw,
    const float* __restrict__ lnb, unsigned short* __restrict__ A1) {
  const int r = blockIdx.x;
  const int tid = threadIdx.x;
  const float4 v = reinterpret_cast<const float4*>(x + (size_t)r * DD)[tid];
  float s = v.x + v.y + v.z + v.w;
#pragma unroll
  for (int off = 32; off >= 1; off >>= 1) s += __shfl_xor(s, off, 64);
  __shared__ float red[8];
  const int wid = tid >> 6;
  if ((tid & 63) == 0) red[wid] = s;
  __syncthreads();
  const float mu = (red[0] + red[1] + red[2] + red[3]) * (1.0f / DD);
  const float dx = v.x - mu, dy = v.y - mu, dz = v.z - mu, dw = v.w - mu;
  float ss = dx * dx + dy * dy + dz * dz + dw * dw;
#pragma unroll
  for (int off = 32; off >= 1; off >>= 1) ss += __shfl_xor(ss, off, 64);
  if ((tid & 63) == 0) red[4 + wid] = ss;
  __syncthreads();
  const float var = (red[4] + red[5] + red[6] + red[7]) * (1.0f / DD);
  const float rs = rsqrtf(var + 1e-5f);
  const float4 w4 = reinterpret_cast<const float4*>(lnw)[tid];
  const float4 b4 = reinterpret_cast<const float4*>(lnb)[tid];
  ushort4 h4;
  h4.x = f2h(dx * rs * w4.x + b4.x);
  h4.y = f2h(dy * rs * w4.y + b4.y);
  h4.z = f2h(dz * rs * w4.z + b4.z);
  h4.w = f2h(dw * rs * w4.w + b4.w);
  *reinterpret_cast<ushort4*>(&A1[(size_t)r * DD + tid * 4]) = h4;
}

// ------------- in_proj_w -> fp16 B1, ssm rows (n<2048) pre-scaled by --------
// 0.5 * d_n  where d_n = sum_s B_mat[n,s]*C_mat[n,s]   (dh folded into W).
__global__ __launch_bounds__(256) void wconv1_kernel(
    const float* __restrict__ W, const float* __restrict__ Bm,
    const float* __restrict__ Cm, unsigned short* __restrict__ B1) {
  const int n = blockIdx.x;
  const int tid = threadIdx.x;
  float scale = 1.f;
  if (n < DI) {
    float d = 0.f;
#pragma unroll
    for (int s = 0; s < DS; ++s)
      d += Bm[(size_t)n * DS + s] * Cm[(size_t)n * DS + s];
    scale = 0.5f * d;
  }
  const float4 w = reinterpret_cast<const float4*>(W + (size_t)n * DD)[tid];
  ushort4 h4;
  h4.x = f2h(w.x * scale); h4.y = f2h(w.y * scale);
  h4.z = f2h(w.z * scale); h4.w = f2h(w.w * scale);
  reinterpret_cast<ushort4*>(B1 + (size_t)n * DD)[tid] = h4;
}

// ------------- generic fp32 -> fp16 converter (for out_proj_w) --------------
__global__ __launch_bounds__(256) void f32_to_f16_kernel(
    const float* __restrict__ W, unsigned short* __restrict__ O) {
  const int gid = blockIdx.x * 256 + threadIdx.x;
  const float4 w = reinterpret_cast<const float4*>(W)[gid];
  ushort4 h4;
  h4.x = f2h(w.x); h4.y = f2h(w.y); h4.z = f2h(w.z); h4.w = f2h(w.w);
  reinterpret_cast<ushort4*>(O)[gid] = h4;
}

// ------------- bidirectional scalar filter on xn:  xs = (F_fwd+F_bwd)(xn) ---
// F_fwd: g_t = x_t + 0.01 g_{t-1};  F_bwd mirrored.  Chunk T=32, halo KH=8
// (error <= 10*0.01^8).  Linear (clip provably inactive) => commutes with the
// channel GEMM.  ushort2-vectorized, 1024 channels.
__global__ __launch_bounds__(256) void filter_kernel(
    const unsigned short* __restrict__ xn, unsigned short* __restrict__ xs) {
  constexpr int T = 32, KH = 8;
  const int blk = blockIdx.x;          // grid 512
  const int igrp = blk & 1;            // 2 channel groups of 512
  const int c = (blk >> 1) & 63;       // 64 time chunks
  const int b = blk >> 7;              // 4 batches
  const int tid = threadIdx.x;
  const int i0 = igrp * 512 + tid * 2;
  const int t0 = c * T;
  const size_t rowbase = (size_t)b * LL;
  float yf0[T], yf1[T];
  float g0 = 0.f, g1 = 0.f;
  {
    const int hstart = (t0 >= KH) ? t0 - KH : 0;
    for (int t = hstart; t < t0; ++t) {
      const unsigned int u = *reinterpret_cast<const unsigned int*>(
          xn + (rowbase + t) * (size_t)DD + i0);
      g0 = fmaf(0.01f, g0, h2f((unsigned short)(u & 0xffff)));
      g1 = fmaf(0.01f, g1, h2f((unsigned short)(u >> 16)));
    }
#pragma unroll
    for (int j = 0; j < T; ++j) {
      const unsigned int u = *reinterpret_cast<const unsigned int*>(
          xn + (rowbase + t0 + j) * (size_t)DD + i0);
      g0 = fmaf(0.01f, g0, h2f((unsigned short)(u & 0xffff)));
      g1 = fmaf(0.01f, g1, h2f((unsigned short)(u >> 16)));
      yf0[j] = g0; yf1[j] = g1;
    }
  }
  g0 = 0.f; g1 = 0.f;
  {
    const int tend = (t0 + T - 1 + KH <= LL - 1) ? (t0 + T - 1 + KH) : (LL - 1);
    for (int t = tend; t >= t0 + T; --t) {
      const unsigned int u = *reinterpret_cast<const unsigned int*>(
          xn + (rowbase + t) * (size_t)DD + i0);
      g0 = fmaf(0.01f, g0, h2f((unsigned short)(u & 0xffff)));
      g1 = fmaf(0.01f, g1, h2f((unsigned short)(u >> 16)));
    }
#pragma unroll
    for (int j = T - 1; j >= 0; --j) {
      const size_t row = rowbase + t0 + j;
      const unsigned int u = *reinterpret_cast<const unsigned int*>(
          xn + row * (size_t)DD + i0);
      g0 = fmaf(0.01f, g0, h2f((unsigned short)(u & 0xffff)));
      g1 = fmaf(0.01f, g1, h2f((unsigned short)(u >> 16)));
      const unsigned int up =
          (unsigned int)f2h(yf0[j] + g0) | ((unsigned int)f2h(yf1[j] + g1) << 16);
      *reinterpret_cast<unsigned int*>(xs + row * (size_t)DD + i0) = up;
    }
  }
}

// ======== fused GEMM: [xs@W'ssm | xn@Wgate] -> OSS = ssm * silu(gate) =======
// Output tile 256 rows x 128 channels (ssm) colocated with its gate tile.
// Virtual 256-col tile: waves wn0-1 -> ssm (A=xs), wn2-3 -> gate (A=xn).
// B staged 256 rows: 0..127 = W'ssm[bn*128..], 128..255 = Wgate[bn*128..].
// BK=32, 2 LDS buffers x 3 regions x 16KB = 96 KB; r10 loop discipline
// (stage(t+1) -> reads -> MFMA -> __syncthreads); r12 conflict-free swizzle:
// chunk c8 of row r at c8 ^ ((r>>1)&3).
// Epilogue: gate waves -> silu fp16 -> LDS gl[256][132]; barrier; ssm waves
// multiply and write OSS directly (no XP round-trip, scan kernel eliminated).
__global__ __launch_bounds__(512, 2) void gemm_fused(
    const unsigned short* __restrict__ XS, const unsigned short* __restrict__ XN,
    const unsigned short* __restrict__ W, unsigned short* __restrict__ OSS) {
  __shared__ unsigned short sm[2][3][8192];  // 96 KB
  const int tid = threadIdx.x;
  const int wid = tid >> 6;
  const int lane = tid & 63;
  const int wm = wid >> 2;   // 0..1
  const int wn = wid & 3;    // 0..3
  const int mt = MROWS >> 8;           // 32
  const int cpx = gridDim.x >> 3;      // 64
  const int bid = blockIdx.x;
  const int sw = (bid & 7) * cpx + (bid >> 3);
  const int bm = sw % mt;
  const int bn = sw / mt;              // 0..15
  const size_t arow0 = (size_t)bm * 256;

  // staging source pointers (pre-swizzled, BK=32: 4 chunks/row)
  const unsigned short* gXS[2];
  const unsigned short* gXN[2];
  const unsigned short* gW[2];
#pragma unroll
  for (int j = 0; j < 2; ++j) {
    const int idx = j * 512 + tid;          // 0..1023
    const int prow = idx >> 2;              // 0..255
    const int scol = ((idx & 3) ^ ((prow >> 1) & 3)) << 3;
    gXS[j] = XS + (arow0 + prow) * (size_t)K1 + scol;
    gXN[j] = XN + (arow0 + prow) * (size_t)K1 + scol;
    const int brow = (prow < 128) ? (bn * 128 + prow)
                                  : (DI + bn * 128 + (prow - 128));
    gW[j] = W + (size_t)brow * K1 + scol;
  }
  auto stage = [&](int buf) {
#pragma unroll
    for (int j = 0; j < 2; ++j) {
      __builtin_amdgcn_global_load_lds((const GLOBAL_AS void*)gXS[j],
          (LDS_AS void*)&sm[buf][0][(j * 512 + tid) * 8], 16, 0, 0);
      gXS[j] += 32;
    }
#pragma unroll
    for (int j = 0; j < 2; ++j) {
      __builtin_amdgcn_global_load_lds((const GLOBAL_AS void*)gXN[j],
          (LDS_AS void*)&sm[buf][1][(j * 512 + tid) * 8], 16, 0, 0);
      gXN[j] += 32;
    }
#pragma unroll
    for (int j = 0; j < 2; ++j) {
      __builtin_amdgcn_global_load_lds((const GLOBAL_AS void*)gW[j],
          (LDS_AS void*)&sm[buf][2][(j * 512 + tid) * 8], 16, 0, 0);
      gW[j] += 32;
    }
  };

  const int q = lane >> 4;
  const int fr = lane & 15;
  const int swzk = ((q ^ ((fr >> 1) & 3)) << 3);
  const int areg = (wn >= 2) ? 1 : 0;   // ssm waves read xs, gate waves xn

  int arows[8], brows[4];
#pragma unroll
  for (int mf = 0; mf < 8; ++mf) arows[mf] = ((wm << 7) + mf * 16 + fr) * 32;
#pragma unroll
  for (int nf = 0; nf < 4; ++nf) brows[nf] = ((wn << 6) + nf * 16 + fr) * 32;

  f32x4 acc[8][4] = {};

  const int NTK = K1 >> 5;  // 32
  stage(0);
  __syncthreads();

  for (int t = 0; t < NTK; ++t) {
    const int cur = t & 1, nxt = cur ^ 1;
    if (t + 1 < NTK) stage(nxt);
    f16x8 af[8], bf[4];
#pragma unroll
    for (int mf = 0; mf < 8; ++mf)
      af[mf] = *reinterpret_cast<const f16x8*>(&sm[cur][areg][arows[mf] + swzk]);
#pragma unroll
    for (int nf = 0; nf < 4; ++nf)
      bf[nf] = *reinterpret_cast<const f16x8*>(&sm[cur][2][brows[nf] + swzk]);
#pragma unroll
    for (int mf = 0; mf < 8; ++mf)
#pragma unroll
      for (int nf = 0; nf < 4; ++nf)
        acc[mf][nf] = __builtin_amdgcn_mfma_f32_16x16x32_f16(
            af[mf], bf[nf], acc[mf][nf], 0, 0, 0);
    __syncthreads();
  }

  // ---- epilogue: gate -> silu -> LDS, then ssm * silu -> OSS ----
  unsigned short* gl = &sm[0][0][0];   // 256 x 132 fp16 = 67.5 KB (LDS free)
  const int fcol = lane & 15;
  const int frow4 = (lane >> 4) << 2;
  if (wn >= 2) {
#pragma unroll
    for (int mf = 0; mf < 8; ++mf)
#pragma unroll
      for (int nf = 0; nf < 4; ++nf) {
        const int gcol = ((wn - 2) << 6) + nf * 16 + fcol;
        const int r0 = (wm << 7) + mf * 16 + frow4;
#pragma unroll
        for (int j = 0; j < 4; ++j) {
          const float g = acc[mf][nf][j];
          gl[(r0 + j) * 132 + gcol] = f2h(g / (1.f + expf(-g)));
        }
      }
  }
  __syncthreads();
  if (wn < 2) {
#pragma unroll
    for (int mf = 0; mf < 8; ++mf)
#pragma unroll
      for (int nf = 0; nf < 4; ++nf) {
        const int scol = (wn << 6) + nf * 16 + fcol;
        const int r0 = (wm << 7) + mf * 16 + frow4;
#pragma unroll
        for (int j = 0; j < 4; ++j) {
          const float o = acc[mf][nf][j] * h2f(gl[(r0 + j) * 132 + scol]);
          OSS[(arow0 + r0 + j) * (size_t)DI + bn * 128 + scol] = f2h(o);
        }
      }
  }
}

// ===== 256x128 tile, BK=64, 8-wave, swizzled un-pinned GEMM (fp16 -> fp32) ==
__global__ __launch_bounds__(512, 2) void gemm_bt_256n128(
    const unsigned short* __restrict__ A, const unsigned short* __restrict__ B,
    float* __restrict__ C, int M, int N, int K) {
  __shared__ unsigned short sm[2][24576];  // [buf][A 16384 | B 8192] = 96 KB
  const int tid = threadIdx.x;
  const int wid = tid >> 6;
  const int lane = tid & 63;
  const int wm = wid >> 2;
  const int wn = wid & 3;
  const int mt = M >> 8;
  const int cpx = gridDim.x >> 3;
  const int bid = blockIdx.x;
  const int sw = (bid & 7) * cpx + (bid >> 3);
  const int bm = sw % mt;
  const int bn = sw / mt;
  const size_t arow0 = (size_t)bm * 256;
  const size_t brow0 = (size_t)bn * 128;

  const unsigned short* gA[4];
  const unsigned short* gB[2];
#pragma unroll
  for (int j = 0; j < 4; ++j) {
    const int idx = j * 512 + tid;
    const int prow = idx >> 3;
    const int scol = ((idx & 7) ^ (prow & 7)) << 3;
    gA[j] = A + (arow0 + prow) * (size_t)K + scol;
  }
#pragma unroll
  for (int j = 0; j < 2; ++j) {
    const int idx = j * 512 + tid;
    const int prow = idx >> 3;
    const int scol = ((idx & 7) ^ (prow & 7)) << 3;
    gB[j] = B + (brow0 + prow) * (size_t)K + scol;
  }
  auto stageA = [&](int buf) {
#pragma unroll
    for (int j = 0; j < 4; ++j) {
      __builtin_amdgcn_global_load_lds((const GLOBAL_AS void*)gA[j],
          (LDS_AS void*)&sm[buf][(j * 512 + (wid << 6)) * 8], 16, 0, 0);
      gA[j] += 64;
    }
  };
  auto stageB = [&](int buf) {
#pragma unroll
    for (int j = 0; j < 2; ++j) {
      __builtin_amdgcn_global_load_lds((const GLOBAL_AS void*)gB[j],
          (LDS_AS void*)&sm[buf][16384 + (j * 512 + (wid << 6)) * 8], 16, 0, 0);
      gB[j] += 64;
    }
  };

  const int q = lane >> 4;
  const int l7 = lane & 7;
  const int fr = lane & 15;
  int swz[2];
  swz[0] = (q << 3) ^ (l7 << 3);
  swz[1] = (32 + (q << 3)) ^ (l7 << 3);

  int arows[8], brows[2];
#pragma unroll
  for (int mf = 0; mf < 8; ++mf) arows[mf] = ((wm << 7) + mf * 16 + fr) * 64;
#pragma unroll
  for (int nf = 0; nf < 2; ++nf) brows[nf] = 16384 + ((wn << 5) + nf * 16 + fr) * 64;

  f32x4 acc[8][2] = {};

  const int NTK = K >> 6;
  stageA(0);
  stageB(0);
  __syncthreads();

  for (int t = 0; t < NTK; ++t) {
    const int cur = t & 1, nxt = cur ^ 1;
    if (t + 1 < NTK) { stageA(nxt); stageB(nxt); }
    f16x8 af[8][2], bf[2][2];
#pragma unroll
    for (int mf = 0; mf < 8; ++mf)
#pragma unroll
      for (int ks = 0; ks < 2; ++ks)
        af[mf][ks] = *reinterpret_cast<const f16x8*>(&sm[cur][arows[mf] + swz[ks]]);
#pragma unroll
    for (int nf = 0; nf < 2; ++nf)
#pragma unroll
      for (int ks = 0; ks < 2; ++ks)
        bf[nf][ks] = *reinterpret_cast<const f16x8*>(&sm[cur][brows[nf] + swz[ks]]);
#pragma unroll
    for (int ks = 0; ks < 2; ++ks)
#pragma unroll
      for (int mf = 0; mf < 8; ++mf)
#pragma unroll
        for (int nf = 0; nf < 2; ++nf)
          acc[mf][nf] = __builtin_amdgcn_mfma_f32_16x16x32_f16(
              af[mf][ks], bf[nf][ks], acc[mf][nf], 0, 0, 0);
    __syncthreads();
  }

  const int fcol = lane & 15;
  const int frow4 = (lane >> 4) << 2;
#pragma unroll
  for (int mf = 0; mf < 8; ++mf)
#pragma unroll
    for (int nf = 0; nf < 2; ++nf) {
      const size_t row0 = arow0 + (wm << 7) + mf * 16 + frow4;
      const size_t col = brow0 + (wn << 5) + nf * 16 + fcol;
#pragma unroll
      for (int j = 0; j < 4; ++j)
        C[(row0 + j) * (size_t)N + col] = acc[mf][nf][j];
    }
}

extern "C" void kernel_launch(void* const* d_in, const int* in_sizes, int n_in,
                              void* d_out, int out_size, void* d_ws, size_t ws_size,
                              hipStream_t stream) {
  (void)in_sizes; (void)n_in; (void)out_size; (void)ws_size;
  const float* x          = (const float*)d_in[0];
  const float* in_proj_w  = (const float*)d_in[1];
  const float* B_mat      = (const float*)d_in[3];
  const float* C_mat      = (const float*)d_in[4];
  const float* out_proj_w = (const float*)d_in[5];
  const float* ln_w       = (const float*)d_in[6];
  const float* ln_b       = (const float*)d_in[7];
  float* out = (float*)d_out;

  char* ws = (char*)d_ws;
  unsigned short* A1  = (unsigned short*)ws; ws += (size_t)MROWS * K1 * 2;  // 16.8 MB
  unsigned short* B1  = (unsigned short*)ws; ws += (size_t)N1 * K1 * 2;    //  8.4 MB
  unsigned short* B2  = (unsigned short*)ws; ws += (size_t)N2 * K2 * 2;    //  4.2 MB
  unsigned short* OSS = (unsigned short*)ws; ws += (size_t)MROWS * DI * 2; // 33.6 MB
  unsigned short* XS  = (unsigned short*)ws; ws += (size_t)MROWS * K1 * 2; // 16.8 MB

  wconv1_kernel<<<dim3(N1), dim3(256), 0, stream>>>(in_proj_w, B_mat, C_mat, B1);
  f32_to_f16_kernel<<<dim3((N2 * K2 / 4) / 256), dim3(256), 0, stream>>>(out_proj_w, B2);
  ln_half_kernel<<<dim3(MROWS), dim3(256), 0, stream>>>(x, ln_w, ln_b, A1);
  filter_kernel<<<dim3(512), dim3(256), 0, stream>>>(A1, XS);
  gemm_fused<<<dim3((MROWS / 256) * (DI / 128)), dim3(512), 0, stream>>>(XS, A1, B1, OSS);
  gemm_bt_256n128<<<dim3((MROWS / 256) * (N2 / 128)), dim3(512), 0, stream>>>(OSS, B2, out, MROWS, N2, K2);
}

// Round 17
// 186.828 us; speedup vs baseline: 1.0363x; 1.0363x over previous
//
#include <hip/hip_runtime.h>

typedef __attribute__((ext_vector_type(8))) _Float16 f16x8;
typedef __attribute__((ext_vector_type(4))) float f32x4;

#define GLOBAL_AS __attribute__((address_space(1)))
#define LDS_AS __attribute__((address_space(3)))

static constexpr int Bb = 4, LL = 2048, DD = 1024, DI = 2048, DS = 16;
static constexpr int MROWS = Bb * LL;   // 8192
static constexpr int N1 = 2 * DI;       // 4096
static constexpr int K1 = DD;           // 1024
static constexpr int N2 = DD;           // 1024
static constexpr int K2 = DI;           // 2048

__device__ __forceinline__ unsigned short f2h(float f) {
  _Float16 h = (_Float16)f;
  union { _Float16 h; unsigned short u; } c; c.h = h;
  return c.u;
}
__device__ __forceinline__ float h2f(unsigned short u) {
  union { unsigned short u; _Float16 h; } c; c.u = u;
  return (float)c.h;
}

// ---------------- LayerNorm -> fp16 A1h [8192][1024] ------------------------
__global__ __launch_bounds__(256) void ln_half_kernel(
    const float* __restrict__ x, const float* __restrict__ lnw,
    const float* __restrict__ lnb, unsigned short* __restrict__ A1) {
  const int r = blockIdx.x;
  const int tid = threadIdx.x;
  const float4 v = reinterpret_cast<const float4*>(x + (size_t)r * DD)[tid];
  float s = v.x + v.y + v.z + v.w;
#pragma unroll
  for (int off = 32; off >= 1; off >>= 1) s += __shfl_xor(s, off, 64);
  __shared__ float red[8];
  const int wid = tid >> 6;
  if ((tid & 63) == 0) red[wid] = s;
  __syncthreads();
  const float mu = (red[0] + red[1] + red[2] + red[3]) * (1.0f / DD);
  const float dx = v.x - mu, dy = v.y - mu, dz = v.z - mu, dw = v.w - mu;
  float ss = dx * dx + dy * dy + dz * dz + dw * dw;
#pragma unroll
  for (int off = 32; off >= 1; off >>= 1) ss += __shfl_xor(ss, off, 64);
  if ((tid & 63) == 0) red[4 + wid] = ss;
  __syncthreads();
  const float var = (red[4] + red[5] + red[6] + red[7]) * (1.0f / DD);
  const float rs = rsqrtf(var + 1e-5f);
  const float4 w4 = reinterpret_cast<const float4*>(lnw)[tid];
  const float4 b4 = reinterpret_cast<const float4*>(lnb)[tid];
  ushort4 h4;
  h4.x = f2h(dx * rs * w4.x + b4.x);
  h4.y = f2h(dy * rs * w4.y + b4.y);
  h4.z = f2h(dz * rs * w4.z + b4.z);
  h4.w = f2h(dw * rs * w4.w + b4.w);
  *reinterpret_cast<ushort4*>(&A1[(size_t)r * DD + tid * 4]) = h4;
}

// ------ merged fp32->fp16 converter: blocks [0,4096) -> B1, rest -> B2 ------
__global__ __launch_bounds__(256) void wcvt_kernel(
    const float* __restrict__ W1, const float* __restrict__ W2,
    unsigned short* __restrict__ B1, unsigned short* __restrict__ B2) {
  constexpr int NB1 = (N1 * K1 / 4) / 256;  // 4096
  const int gid = blockIdx.x * 256 + threadIdx.x;
  const float* src; unsigned short* dst; int idx;
  if (blockIdx.x < NB1) { src = W1; dst = B1; idx = gid; }
  else { src = W2; dst = B2; idx = gid - NB1 * 256; }
  const float4 w = reinterpret_cast<const float4*>(src)[idx];
  ushort4 h4;
  h4.x = f2h(w.x); h4.y = f2h(w.y); h4.z = f2h(w.z); h4.w = f2h(w.w);
  reinterpret_cast<ushort4*>(dst)[idx] = h4;
}

// ======== 256x256 tile, BK=64, 8-wave, swizzled-LDS GEMM (fp16) =============
// C[M][N] = A[M][K] * B[N][K]^T, output fp16.  K-loop = round-10 (measured
// best); epilogue = LDS-staged coalesced 512B-row stores (round-15).
__global__ __launch_bounds__(512, 2) void gemm_bt_256(
    const unsigned short* __restrict__ A, const unsigned short* __restrict__ B,
    unsigned short* __restrict__ C, int M, int N, int K) {
  __shared__ __align__(16) unsigned short smu[67584];  // 135168 B
  auto sm = reinterpret_cast<unsigned short (*)[2][256 * 64]>(smu);
  const int tid = threadIdx.x;
  const int wid = tid >> 6;
  const int lane = tid & 63;
  const int wm = wid >> 2;   // 0..1
  const int wn = wid & 3;    // 0..3
  const int mt = M >> 8;
  const int cpx = gridDim.x >> 3;
  const int bid = blockIdx.x;
  const int sw = (bid & 7) * cpx + (bid >> 3);
  const int bm = sw % mt;
  const int bn = sw / mt;
  const size_t arow0 = (size_t)bm * 256;
  const size_t brow0 = (size_t)bn * 256;

  const unsigned short* gA[4];
  const unsigned short* gB[4];
#pragma unroll
  for (int j = 0; j < 4; ++j) {
    const int idx = j * 512 + tid;
    const int prow = idx >> 3;
    const int scol = ((idx & 7) ^ (prow & 7)) << 3;
    gA[j] = A + (arow0 + prow) * (size_t)K + scol;
    gB[j] = B + (brow0 + prow) * (size_t)K + scol;
  }
  auto stageA = [&](int buf) {
#pragma unroll
    for (int j = 0; j < 4; ++j) {
      __builtin_amdgcn_global_load_lds((const GLOBAL_AS void*)gA[j],
          (LDS_AS void*)&sm[buf][0][(j * 512 + (wid << 6)) * 8], 16, 0, 0);
      gA[j] += 64;
    }
  };
  auto stageB = [&](int buf) {
#pragma unroll
    for (int j = 0; j < 4; ++j) {
      __builtin_amdgcn_global_load_lds((const GLOBAL_AS void*)gB[j],
          (LDS_AS void*)&sm[buf][1][(j * 512 + (wid << 6)) * 8], 16, 0, 0);
      gB[j] += 64;
    }
  };

  const int q = lane >> 4;
  const int l7 = lane & 7;
  const int fr = lane & 15;
  int swz[2];
  swz[0] = (q << 3) ^ (l7 << 3);
  swz[1] = (32 + (q << 3)) ^ (l7 << 3);

  int arows[8], brows[4];
#pragma unroll
  for (int mf = 0; mf < 8; ++mf) arows[mf] = ((wm << 7) + mf * 16 + fr) * 64;
#pragma unroll
  for (int nf = 0; nf < 4; ++nf) brows[nf] = ((wn << 6) + nf * 16 + fr) * 64;

  f32x4 acc[8][4] = {};

  const int NTK = K >> 6;
  stageA(0);
  stageB(0);
  __syncthreads();

  for (int t = 0; t < NTK; ++t) {
    const int cur = t & 1, nxt = cur ^ 1;
    if (t + 1 < NTK) { stageA(nxt); stageB(nxt); }
    f16x8 af[8][2], bf[4][2];
#pragma unroll
    for (int mf = 0; mf < 8; ++mf)
#pragma unroll
      for (int ks = 0; ks < 2; ++ks)
        af[mf][ks] = *reinterpret_cast<const f16x8*>(&sm[cur][0][arows[mf] + swz[ks]]);
#pragma unroll
    for (int nf = 0; nf < 4; ++nf)
#pragma unroll
      for (int ks = 0; ks < 2; ++ks)
        bf[nf][ks] = *reinterpret_cast<const f16x8*>(&sm[cur][1][brows[nf] + swz[ks]]);
#pragma unroll
    for (int ks = 0; ks < 2; ++ks)
#pragma unroll
      for (int mf = 0; mf < 8; ++mf)
#pragma unroll
        for (int nf = 0; nf < 4; ++nf)
          acc[mf][nf] = __builtin_amdgcn_mfma_f32_16x16x32_f16(
              af[mf][ks], bf[nf][ks], acc[mf][nf], 0, 0, 0);
    __syncthreads();
  }

  // ---- epilogue: LDS-staged coalesced C-write ----
  {
    unsigned short* ep = smu;
    const int fcol = lane & 15;
    const int frow4 = (lane >> 4) << 2;
#pragma unroll
    for (int mf = 0; mf < 8; ++mf)
#pragma unroll
      for (int nf = 0; nf < 4; ++nf) {
        const int r0 = (wm << 7) + mf * 16 + frow4;
        const int cc = (wn << 6) + nf * 16 + fcol;
#pragma unroll
        for (int j = 0; j < 4; ++j)
          ep[(r0 + j) * 264 + cc] = f2h(acc[mf][nf][j]);
      }
    __syncthreads();
    const int rr = tid >> 5;          // 0..15
    const int ck = (tid & 31) * 8;    // 16B chunk within row
#pragma unroll
    for (int k = 0; k < 16; ++k) {
      const int r = rr + k * 16;
      const f16x8 v = *reinterpret_cast<const f16x8*>(&ep[r * 264 + ck]);
      *reinterpret_cast<f16x8*>(&C[(arow0 + r) * (size_t)N + brow0 + ck]) = v;
    }
  }
}

// ===== 256x128 tile, BK=64, 8-wave, swizzled un-pinned GEMM (fp16 -> fp32) ==
__global__ __launch_bounds__(512, 2) void gemm_bt_256n128(
    const unsigned short* __restrict__ A, const unsigned short* __restrict__ B,
    float* __restrict__ C, int M, int N, int K) {
  __shared__ unsigned short sm[2][24576];  // [buf][A 16384 | B 8192] = 96 KB
  const int tid = threadIdx.x;
  const int wid = tid >> 6;
  const int lane = tid & 63;
  const int wm = wid >> 2;
  const int wn = wid & 3;
  const int mt = M >> 8;
  const int cpx = gridDim.x >> 3;
  const int bid = blockIdx.x;
  const int sw = (bid & 7) * cpx + (bid >> 3);
  const int bm = sw % mt;
  const int bn = sw / mt;
  const size_t arow0 = (size_t)bm * 256;
  const size_t brow0 = (size_t)bn * 128;

  const unsigned short* gA[4];
  const unsigned short* gB[2];
#pragma unroll
  for (int j = 0; j < 4; ++j) {
    const int idx = j * 512 + tid;
    const int prow = idx >> 3;
    const int scol = ((idx & 7) ^ (prow & 7)) << 3;
    gA[j] = A + (arow0 + prow) * (size_t)K + scol;
  }
#pragma unroll
  for (int j = 0; j < 2; ++j) {
    const int idx = j * 512 + tid;
    const int prow = idx >> 3;
    const int scol = ((idx & 7) ^ (prow & 7)) << 3;
    gB[j] = B + (brow0 + prow) * (size_t)K + scol;
  }
  auto stageA = [&](int buf) {
#pragma unroll
    for (int j = 0; j < 4; ++j) {
      __builtin_amdgcn_global_load_lds((const GLOBAL_AS void*)gA[j],
          (LDS_AS void*)&sm[buf][(j * 512 + (wid << 6)) * 8], 16, 0, 0);
      gA[j] += 64;
    }
  };
  auto stageB = [&](int buf) {
#pragma unroll
    for (int j = 0; j < 2; ++j) {
      __builtin_amdgcn_global_load_lds((const GLOBAL_AS void*)gB[j],
          (LDS_AS void*)&sm[buf][16384 + (j * 512 + (wid << 6)) * 8], 16, 0, 0);
      gB[j] += 64;
    }
  };

  const int q = lane >> 4;
  const int l7 = lane & 7;
  const int fr = lane & 15;
  int swz[2];
  swz[0] = (q << 3) ^ (l7 << 3);
  swz[1] = (32 + (q << 3)) ^ (l7 << 3);

  int arows[8], brows[2];
#pragma unroll
  for (int mf = 0; mf < 8; ++mf) arows[mf] = ((wm << 7) + mf * 16 + fr) * 64;
#pragma unroll
  for (int nf = 0; nf < 2; ++nf) brows[nf] = 16384 + ((wn << 5) + nf * 16 + fr) * 64;

  f32x4 acc[8][2] = {};

  const int NTK = K >> 6;
  stageA(0);
  stageB(0);
  __syncthreads();

  for (int t = 0; t < NTK; ++t) {
    const int cur = t & 1, nxt = cur ^ 1;
    if (t + 1 < NTK) { stageA(nxt); stageB(nxt); }
    f16x8 af[8][2], bf[2][2];
#pragma unroll
    for (int mf = 0; mf < 8; ++mf)
#pragma unroll
      for (int ks = 0; ks < 2; ++ks)
        af[mf][ks] = *reinterpret_cast<const f16x8*>(&sm[cur][arows[mf] + swz[ks]]);
#pragma unroll
    for (int nf = 0; nf < 2; ++nf)
#pragma unroll
      for (int ks = 0; ks < 2; ++ks)
        bf[nf][ks] = *reinterpret_cast<const f16x8*>(&sm[cur][brows[nf] + swz[ks]]);
#pragma unroll
    for (int ks = 0; ks < 2; ++ks)
#pragma unroll
      for (int mf = 0; mf < 8; ++mf)
#pragma unroll
        for (int nf = 0; nf < 2; ++nf)
          acc[mf][nf] = __builtin_amdgcn_mfma_f32_16x16x32_f16(
              af[mf][ks], bf[nf][ks], acc[mf][nf], 0, 0, 0);
    __syncthreads();
  }

  const int fcol = lane & 15;
  const int frow4 = (lane >> 4) << 2;
#pragma unroll
  for (int mf = 0; mf < 8; ++mf)
#pragma unroll
    for (int nf = 0; nf < 2; ++nf) {
      const size_t row0 = arow0 + (wm << 7) + mf * 16 + frow4;
      const size_t col = brow0 + (wn << 5) + nf * 16 + fcol;
#pragma unroll
      for (int j = 0; j < 4; ++j)
        C[(row0 + j) * (size_t)N + col] = acc[mf][nf][j];
    }
}

// ------------- scalar-filter bidirectional scan + SiLU gate (ushort2) -------
__global__ __launch_bounds__(256) void scan_kernel(
    const unsigned short* __restrict__ xp, const float* __restrict__ Bm,
    const float* __restrict__ Cm, unsigned short* __restrict__ oss) {
  constexpr int T = 32, KH = 8;
  const int blk = blockIdx.x;          // grid 1024
  const int igrp = blk & 3;            // 4 channel groups of 512
  const int c = (blk >> 2) & 63;       // 64 time chunks
  const int b = blk >> 8;              // 4 batches
  const int tid = threadIdx.x;
  const int i0 = igrp * 512 + tid * 2;
  float d0 = 0.f, d1 = 0.f;
#pragma unroll
  for (int ch = 0; ch < 2; ++ch) {
    const float4* bp = reinterpret_cast<const float4*>(Bm + (size_t)(i0 + ch) * DS);
    const float4* cp = reinterpret_cast<const float4*>(Cm + (size_t)(i0 + ch) * DS);
    float d = 0.f;
#pragma unroll
    for (int qv = 0; qv < 4; ++qv) {
      const float4 bv = bp[qv], cv = cp[qv];
      d += bv.x * cv.x + bv.y * cv.y + bv.z * cv.z + bv.w * cv.w;
    }
    if (ch == 0) d0 = d; else d1 = d;
  }
  const float dh0 = 0.5f * d0, dh1 = 0.5f * d1;
  const int t0 = c * T;
  const size_t rowbase = (size_t)b * LL;
  float yf0[T], yf1[T];
  float g0 = 0.f, g1 = 0.f;
  {
    const int hstart = (t0 >= KH) ? t0 - KH : 0;
    for (int t = hstart; t < t0; ++t) {
      const unsigned int u = *reinterpret_cast<const unsigned int*>(
          xp + (rowbase + t) * (size_t)N1 + i0);
      g0 = fmaf(0.01f, g0, h2f((unsigned short)(u & 0xffff)));
      g1 = fmaf(0.01f, g1, h2f((unsigned short)(u >> 16)));
    }
#pragma unroll
    for (int j = 0; j < T; ++j) {
      const unsigned int u = *reinterpret_cast<const unsigned int*>(
          xp + (rowbase + t0 + j) * (size_t)N1 + i0);
      g0 = fmaf(0.01f, g0, h2f((unsigned short)(u & 0xffff)));
      g1 = fmaf(0.01f, g1, h2f((unsigned short)(u >> 16)));
      yf0[j] = g0; yf1[j] = g1;
    }
  }
  g0 = 0.f; g1 = 0.f;
  {
    const int tend = (t0 + T - 1 + KH <= LL - 1) ? (t0 + T - 1 + KH) : (LL - 1);
    for (int t = tend; t >= t0 + T; --t) {
      const unsigned int u = *reinterpret_cast<const unsigned int*>(
          xp + (rowbase + t) * (size_t)N1 + i0);
      g0 = fmaf(0.01f, g0, h2f((unsigned short)(u & 0xffff)));
      g1 = fmaf(0.01f, g1, h2f((unsigned short)(u >> 16)));
    }
#pragma unroll
    for (int j = T - 1; j >= 0; --j) {
      const size_t row = rowbase + t0 + j;
      const unsigned int u = *reinterpret_cast<const unsigned int*>(
          xp + row * (size_t)N1 + i0);
      g0 = fmaf(0.01f, g0, h2f((unsigned short)(u & 0xffff)));
      g1 = fmaf(0.01f, g1, h2f((unsigned short)(u >> 16)));
      const unsigned int ug = *reinterpret_cast<const unsigned int*>(
          xp + row * (size_t)N1 + DI + i0);
      const float gt0 = h2f((unsigned short)(ug & 0xffff));
      const float gt1 = h2f((unsigned short)(ug >> 16));
      const float sg0 = gt0 / (1.f + expf(-gt0));
      const float sg1 = gt1 / (1.f + expf(-gt1));
      const float o0 = (yf0[j] + g0) * dh0 * sg0;
      const float o1 = (yf1[j] + g1) * dh1 * sg1;
      const unsigned int up = (unsigned int)f2h(o0) | ((unsigned int)f2h(o1) << 16);
      *reinterpret_cast<unsigned int*>(oss + row * (size_t)DI + i0) = up;
    }
  }
}

extern "C" void kernel_launch(void* const* d_in, const int* in_sizes, int n_in,
                              void* d_out, int out_size, void* d_ws, size_t ws_size,
                              hipStream_t stream) {
  (void)in_sizes; (void)n_in; (void)out_size; (void)ws_size;
  const float* x          = (const float*)d_in[0];
  const float* in_proj_w  = (const float*)d_in[1];
  const float* B_mat      = (const float*)d_in[3];
  const float* C_mat      = (const float*)d_in[4];
  const float* out_proj_w = (const float*)d_in[5];
  const float* ln_w       = (const float*)d_in[6];
  const float* ln_b       = (const float*)d_in[7];
  float* out = (float*)d_out;

  char* ws = (char*)d_ws;
  unsigned short* A1  = (unsigned short*)ws; ws += (size_t)MROWS * K1 * 2;  // 16.8 MB
  unsigned short* B1  = (unsigned short*)ws; ws += (size_t)N1 * K1 * 2;    //  8.4 MB
  unsigned short* B2  = (unsigned short*)ws; ws += (size_t)N2 * K2 * 2;    //  4.2 MB
  unsigned short* OSS = (unsigned short*)ws; ws += (size_t)MROWS * DI * 2; // 33.6 MB
  unsigned short* XP  = (unsigned short*)ws; ws += (size_t)MROWS * N1 * 2; // 67.1 MB

  constexpr int NB1 = (N1 * K1 / 4) / 256;          // 4096 blocks
  constexpr int NB2 = (N2 * K2 / 4) / 256;          // 2048 blocks
  wcvt_kernel<<<dim3(NB1 + NB2), dim3(256), 0, stream>>>(in_proj_w, out_proj_w, B1, B2);
  ln_half_kernel<<<dim3(MROWS), dim3(256), 0, stream>>>(x, ln_w, ln_b, A1);
  gemm_bt_256<<<dim3((MROWS / 256) * (N1 / 256)), dim3(512), 0, stream>>>(A1, B1, XP, MROWS, N1, K1);
  scan_kernel<<<dim3(1024), dim3(256), 0, stream>>>(XP, B_mat, C_mat, OSS);
  gemm_bt_256n128<<<dim3((MROWS / 256) * (N2 / 128)), dim3(512), 0, stream>>>(OSS, B2, out, MROWS, N2, K2);
}